// Round 1
// 1573.547 us; speedup vs baseline: 2.8225x; 2.8225x over previous
//
#include <hip/hip_runtime.h>
#include <hip/hip_bf16.h>
#include <math.h>

#define BATCH 8
#define SEQ   1024
#define DM    768
#define NHEAD 12
#define KVH   4
#define HD    64
#define REP   3

typedef unsigned short u16;
typedef __attribute__((ext_vector_type(8))) __bf16 bf16x8;
typedef __attribute__((ext_vector_type(4))) float f32x4;
typedef __attribute__((ext_vector_type(4))) unsigned int u32x4;

// RTNE fp32 -> bf16 (finite values)
__device__ __forceinline__ u16 f2bf(float f) {
    unsigned int u = __float_as_uint(f);
    u += 0x7fffu + ((u >> 16) & 1u);
    return (u16)(u >> 16);
}

// ======== convert x -> bf16, vectorized (float4 in, ushort4 out) ============
__global__ __launch_bounds__(256) void cvt_x_k(
    const float* __restrict__ in, u16* __restrict__ o, int n4)
{
    const int i = blockIdx.x * 256 + threadIdx.x;
    if (i >= n4) return;
    const float4 v = ((const float4*)in)[i];
    ushort4 r;
    r.x = f2bf(v.x); r.y = f2bf(v.y); r.z = f2bf(v.z); r.w = f2bf(v.w);
    ((ushort4*)o)[i] = r;
}

// ==== build Wt[n][k] bf16 = concat(qw|kw|vw)[k][n] transposed+converted =====
__global__ __launch_bounds__(256) void cvt_wqkv_k(
    const float* __restrict__ qw, const float* __restrict__ kw,
    const float* __restrict__ vw, u16* __restrict__ wt)
{
    const int idx = blockIdx.x * 256 + threadIdx.x;   // idx = n*768 + k
    if (idx >= 1280 * DM) return;
    const int k = idx % DM;
    const int n = idx / DM;
    float v;
    if (n < 768)       v = qw[(size_t)k * 768 + n];
    else if (n < 1024) v = kw[(size_t)k * 256 + (n - 768)];
    else               v = vw[(size_t)k * 256 + (n - 1024)];
    wt[idx] = f2bf(v);
}

__global__ __launch_bounds__(256) void cvt_wo_k(
    const float* __restrict__ ow, u16* __restrict__ wt)
{
    const int idx = blockIdx.x * 256 + threadIdx.x;   // idx = n*768 + k
    if (idx >= DM * DM) return;
    const int k = idx % DM;
    const int n = idx / DM;
    wt[idx] = f2bf(ow[(size_t)k * DM + n]);
}

// ======== 128x128-tile bf16 MFMA GEMM body (single-buffer, BK=32) ===========
// A: [M][768] bf16 row-major.  B: [N][768] bf16 row-major (pre-transposed).
// 4 waves in 2x2; each wave 64x64 via 4x4 fragments of 16x16x32 MFMA.
// A/B fragments use the SAME (lane-group, elem)->k mapping -> contraction is
// permutation-invariant; C/D layout is the HW-verified col=lane&15,
// row=(lane>>4)*4+reg.
__device__ __forceinline__ void gemm128_body(
    const u16* __restrict__ A, const u16* __restrict__ B,
    int m0, int n0, u16* As, u16* Bs, f32x4 acc[4][4])
{
    const int tid  = threadIdx.x;
    const int lane = tid & 63;
    const int wid  = tid >> 6;
    const int wr = wid >> 1, wc = wid & 1;
    const int lo = lane & 15, hi = lane >> 4;

    const f32x4 z = {0.f, 0.f, 0.f, 0.f};
    #pragma unroll
    for (int i = 0; i < 4; i++)
        #pragma unroll
        for (int j = 0; j < 4; j++)
            acc[i][j] = z;

    for (int kt = 0; kt < DM; kt += 32) {
        // stage A-tile [128][32] and B-tile [128][32] (rows = n), bf16x8 chunks
        #pragma unroll
        for (int r = 0; r < 2; ++r) {
            const int idx = r * 256 + tid;          // chunk id, 512 per tile
            const int row = idx >> 2;
            const int col = (idx & 3) << 3;
            *(u32x4*)&As[idx * 8] = *(const u32x4*)&A[(size_t)(m0 + row) * DM + kt + col];
            *(u32x4*)&Bs[idx * 8] = *(const u32x4*)&B[(size_t)(n0 + row) * DM + kt + col];
        }
        __syncthreads();
        bf16x8 af[4], bfr[4];
        #pragma unroll
        for (int i = 0; i < 4; i++) af[i]  = *(const bf16x8*)&As[(wr * 64 + i * 16 + lo) * 32 + hi * 8];
        #pragma unroll
        for (int j = 0; j < 4; j++) bfr[j] = *(const bf16x8*)&Bs[(wc * 64 + j * 16 + lo) * 32 + hi * 8];
        #pragma unroll
        for (int i = 0; i < 4; i++)
            #pragma unroll
            for (int j = 0; j < 4; j++)
                acc[i][j] = __builtin_amdgcn_mfma_f32_16x16x32_bf16(af[i], bfr[j], acc[i][j], 0, 0, 0);
        __syncthreads();
    }
}

// ======== QKV projection: C[8192][1280] -> scatter to Q/K/V head layouts ====
__global__ __launch_bounds__(256) void gemm_qkv(
    const u16* __restrict__ xb, const u16* __restrict__ wt,
    const float* __restrict__ qb, const float* __restrict__ kb,
    const float* __restrict__ vb,
    u16* __restrict__ Q, u16* __restrict__ K, u16* __restrict__ V)
{
    __shared__ __align__(16) u16 As[128 * 32];
    __shared__ __align__(16) u16 Bs[128 * 32];
    const int m0 = blockIdx.x * 128;
    const int n0 = blockIdx.y * 128;
    f32x4 acc[4][4];
    gemm128_body(xb, wt, m0, n0, As, Bs, acc);

    const int tid = threadIdx.x;
    const int lane = tid & 63, wid = tid >> 6;
    const int wr = wid >> 1, wc = wid & 1;
    const int lo = lane & 15, hi = lane >> 4;

    #pragma unroll
    for (int j = 0; j < 4; j++) {
        const int n = n0 + wc * 64 + j * 16 + lo;
        u16* outp; int nl, Hcnt; float bias;
        if (n < 768)       { outp = Q; nl = n;        Hcnt = NHEAD; bias = qb[n];  }
        else if (n < 1024) { outp = K; nl = n - 768;  Hcnt = KVH;   bias = kb[nl]; }
        else               { outp = V; nl = n - 1024; Hcnt = KVH;   bias = vb[nl]; }
        const int head = nl >> 6, d = nl & 63;
        #pragma unroll
        for (int i = 0; i < 4; i++) {
            #pragma unroll
            for (int r = 0; r < 4; r++) {
                const int m = m0 + wr * 64 + i * 16 + hi * 4 + r;
                const int b = m >> 10, t = m & 1023;
                outp[(((size_t)(b * Hcnt + head)) * SEQ + t) * HD + d] =
                    f2bf(acc[i][j][r] + bias);
            }
        }
    }
}

// ======== output projection: attn[8192][768] bf16 @ Wo^T + ob -> fp32 =======
__global__ __launch_bounds__(256) void gemm_oproj(
    const u16* __restrict__ Ab, const u16* __restrict__ wt,
    const float* __restrict__ ob, float* __restrict__ outp)
{
    __shared__ __align__(16) u16 As[128 * 32];
    __shared__ __align__(16) u16 Bs[128 * 32];
    const int m0 = blockIdx.x * 128;
    const int n0 = blockIdx.y * 128;
    f32x4 acc[4][4];
    gemm128_body(Ab, wt, m0, n0, As, Bs, acc);

    const int tid = threadIdx.x;
    const int lane = tid & 63, wid = tid >> 6;
    const int wr = wid >> 1, wc = wid & 1;
    const int lo = lane & 15, hi = lane >> 4;

    #pragma unroll
    for (int j = 0; j < 4; j++) {
        const int n = n0 + wc * 64 + j * 16 + lo;
        const float bias = ob[n];
        #pragma unroll
        for (int i = 0; i < 4; i++) {
            #pragma unroll
            for (int r = 0; r < 4; r++) {
                const int m = m0 + wr * 64 + i * 16 + hi * 4 + r;
                outp[(size_t)m * DM + n] = acc[i][j][r] + bias;
            }
        }
    }
}

// ======== naive RoPE, out-of-place, INTERLEAVED (file-faithful) variant ======
__global__ __launch_bounds__(256) void rope_naive(
    const __hip_bfloat16* __restrict__ in, __hip_bfloat16* __restrict__ outb,
    const int* __restrict__ pos, long long nrows)
{
    const long long gid = (long long)blockIdx.x * 256 + threadIdx.x;
    if (gid >= nrows * 64) return;
    const long long row = gid >> 6;
    const int j = (int)(gid & 63);
    const int t = (int)(row & (SEQ - 1));

    float p;
    if (pos[1] == 1)                              p = (float)pos[t];
    else if (((const float*)pos)[1] == 1.0f)      p = ((const float*)pos)[t];
    else                                          p = (float)pos[2 * t];

    const float inv = exp2f(-(float)(j & 31) * (13.287712379549449f / 32.0f));
    float sv, cv;
    sincosf(p * inv, &sv, &cv);
    const int partner = (j & 1) * 32 + (j >> 1) + ((j < 32) ? 16 : -16);
    const float sign  = (j < 32) ? -1.0f : 1.0f;
    const float val  = __bfloat162float(in[row * HD + j]);
    const float pv   = __bfloat162float(in[row * HD + partner]);
    outb[row * HD + j] = __float2bfloat16(val * cv + sign * pv * sv);
}

// ======== naive causal grouped attention, g = h / REP (file-faithful) ========
__global__ __launch_bounds__(64) void attn_naive(
    const __hip_bfloat16* __restrict__ Q, const __hip_bfloat16* __restrict__ K,
    const __hip_bfloat16* __restrict__ V, __hip_bfloat16* __restrict__ outp)
{
    const int bid = blockIdx.x;                 // b*(NHEAD*SEQ) + h*SEQ + t
    const int b   = bid / (NHEAD * SEQ);
    const int rem = bid % (NHEAD * SEQ);
    const int h   = rem / SEQ;
    const int t   = rem % SEQ;
    const int g   = h / REP;
    const int lane = threadIdx.x;               // 0..63

    const __hip_bfloat16* q  = Q + ((size_t)(b * NHEAD + h) * SEQ + t) * HD;
    const __hip_bfloat16* Kb = K + (size_t)(b * KVH + g) * SEQ * HD;
    const __hip_bfloat16* Vb = V + (size_t)(b * KVH + g) * SEQ * HD;

    __shared__ float p[SEQ];
    __shared__ float partial[64];
    __shared__ float qs[64];
    __shared__ float linv_s;

    qs[lane] = __bfloat162float(q[lane]);
    __syncthreads();

    float psum = 0.f;
    for (int s = lane; s <= t; s += 64) {
        float acc = 0.f;
        for (int d = 0; d < HD; d++)
            acc += qs[d] * __bfloat162float(Kb[(size_t)s * HD + d]);
        const float e = expf(acc * 0.125f);
        p[s] = e;
        psum += e;
    }
    partial[lane] = psum;
    __syncthreads();
    if (lane == 0) {
        float l = 0.f;
        for (int i = 0; i < 64; i++) l += partial[i];
        linv_s = 1.0f / fmaxf(l, 1e-37f);
    }
    __syncthreads();
    const float linv = linv_s;

    float acc = 0.f;
    for (int s = 0; s <= t; s++)
        acc += p[s] * __bfloat162float(Vb[(size_t)s * HD + lane]);

    outp[((size_t)(b * SEQ + t)) * DM + h * HD + lane] = __float2bfloat16(acc * linv);
}

extern "C" void kernel_launch(void* const* d_in, const int* in_sizes, int n_in,
                              void* d_out, int out_size, void* d_ws, size_t ws_size,
                              hipStream_t stream) {
    const float* x   = (const float*)d_in[0];
    const int*   pos = (const int*)d_in[1];
    const float* qw  = (const float*)d_in[2];
    const float* qb  = (const float*)d_in[3];
    const float* kw  = (const float*)d_in[4];
    const float* kb  = (const float*)d_in[5];
    const float* vw  = (const float*)d_in[6];
    const float* vb  = (const float*)d_in[7];
    const float* ow  = (const float*)d_in[8];
    const float* ob  = (const float*)d_in[9];
    float* out = (float*)d_out;                 // OUTPUT IS FP32

    // ws carve (u16 elements), ~39 MB total with lifetime-based reuse:
    //   xb [8192*768] -> reused as Qrot after gemm_qkv consumes it
    //   Qbuf          -> reused as attn output after rope consumes it
    u16* xb    = (u16*)d_ws;                                    // 6291456
    u16* Wqkvt = xb    + (size_t)8192 * DM;                     //  983040
    u16* Wot   = Wqkvt + (size_t)1280 * DM;                     //  589824
    u16* Qbuf  = Wot   + (size_t)DM * DM;                       // 6291456
    u16* Kbuf  = Qbuf  + (size_t)BATCH * NHEAD * SEQ * HD;      // 2097152
    u16* Krot  = Kbuf  + (size_t)BATCH * KVH * SEQ * HD;        // 2097152
    u16* Vbuf  = Krot  + (size_t)BATCH * KVH * SEQ * HD;        // 2097152
    u16* Qrot  = xb;     // alias: xb dead after gemm_qkv
    u16* attn  = Qbuf;   // alias: Qbuf dead after rope_q

    cvt_x_k<<<(8192 * DM / 4 + 255) / 256, 256, 0, stream>>>(x, xb, 8192 * DM / 4);
    cvt_wqkv_k<<<(1280 * DM + 255) / 256, 256, 0, stream>>>(qw, kw, vw, Wqkvt);
    cvt_wo_k<<<(DM * DM + 255) / 256, 256, 0, stream>>>(ow, Wot);

    dim3 gq(64, 10);   // M/128=64, N/128=10 (N=1280)
    gemm_qkv<<<gq, 256, 0, stream>>>(xb, Wqkvt, qb, kb, vb, Qbuf, Kbuf, Vbuf);

    const long long qrows = (long long)BATCH * NHEAD * SEQ;   // 98304
    const long long krows = (long long)BATCH * KVH * SEQ;     // 32768
    rope_naive<<<(int)((qrows * 64 + 255) / 256), 256, 0, stream>>>(
        (const __hip_bfloat16*)Qbuf, (__hip_bfloat16*)Qrot, pos, qrows);
    rope_naive<<<(int)((krows * 64 + 255) / 256), 256, 0, stream>>>(
        (const __hip_bfloat16*)Kbuf, (__hip_bfloat16*)Krot, pos, krows);

    attn_naive<<<BATCH * NHEAD * SEQ, 64, 0, stream>>>(
        (const __hip_bfloat16*)Qrot, (const __hip_bfloat16*)Krot,
        (const __hip_bfloat16*)Vbuf, (__hip_bfloat16*)attn);

    dim3 go(64, 6);    // N=768
    gemm_oproj<<<go, 256, 0, stream>>>(attn, Wot, ob, out);
}

// Round 2
// 459.502 us; speedup vs baseline: 9.6654x; 3.4245x over previous
//
#include <hip/hip_runtime.h>
#include <hip/hip_bf16.h>
#include <math.h>

#define BATCH 8
#define SEQ   1024
#define DM    768
#define NHEAD 12
#define KVH   4
#define HD    64
#define REP   3

typedef unsigned short u16;
typedef __attribute__((ext_vector_type(8))) __bf16 bf16x8;
typedef __attribute__((ext_vector_type(4))) float f32x4;
typedef __attribute__((ext_vector_type(4))) unsigned int u32x4;

// RTNE fp32 -> bf16 (finite values)
__device__ __forceinline__ u16 f2bf(float f) {
    unsigned int u = __float_as_uint(f);
    u += 0x7fffu + ((u >> 16) & 1u);
    return (u16)(u >> 16);
}

// ======== convert x -> bf16, vectorized (float4 in, ushort4 out) ============
__global__ __launch_bounds__(256) void cvt_x_k(
    const float* __restrict__ in, u16* __restrict__ o, int n4)
{
    const int i = blockIdx.x * 256 + threadIdx.x;
    if (i >= n4) return;
    const float4 v = ((const float4*)in)[i];
    ushort4 r;
    r.x = f2bf(v.x); r.y = f2bf(v.y); r.z = f2bf(v.z); r.w = f2bf(v.w);
    ((ushort4*)o)[i] = r;
}

// ==== build Wt[n][k] bf16 = concat(qw|kw|vw)[k][n] transposed+converted =====
__global__ __launch_bounds__(256) void cvt_wqkv_k(
    const float* __restrict__ qw, const float* __restrict__ kw,
    const float* __restrict__ vw, u16* __restrict__ wt)
{
    const int idx = blockIdx.x * 256 + threadIdx.x;   // idx = n*768 + k
    if (idx >= 1280 * DM) return;
    const int k = idx % DM;
    const int n = idx / DM;
    float v;
    if (n < 768)       v = qw[(size_t)k * 768 + n];
    else if (n < 1024) v = kw[(size_t)k * 256 + (n - 768)];
    else               v = vw[(size_t)k * 256 + (n - 1024)];
    wt[idx] = f2bf(v);
}

__global__ __launch_bounds__(256) void cvt_wo_k(
    const float* __restrict__ ow, u16* __restrict__ wt)
{
    const int idx = blockIdx.x * 256 + threadIdx.x;   // idx = n*768 + k
    if (idx >= DM * DM) return;
    const int k = idx % DM;
    const int n = idx / DM;
    wt[idx] = f2bf(ow[(size_t)k * DM + n]);
}

// ======== 128x128-tile bf16 MFMA GEMM body (single-buffer, BK=32) ===========
__device__ __forceinline__ void gemm128_body(
    const u16* __restrict__ A, const u16* __restrict__ B,
    int m0, int n0, u16* As, u16* Bs, f32x4 acc[4][4])
{
    const int tid  = threadIdx.x;
    const int lane = tid & 63;
    const int wid  = tid >> 6;
    const int wr = wid >> 1, wc = wid & 1;
    const int lo = lane & 15, hi = lane >> 4;

    const f32x4 z = {0.f, 0.f, 0.f, 0.f};
    #pragma unroll
    for (int i = 0; i < 4; i++)
        #pragma unroll
        for (int j = 0; j < 4; j++)
            acc[i][j] = z;

    for (int kt = 0; kt < DM; kt += 32) {
        #pragma unroll
        for (int r = 0; r < 2; ++r) {
            const int idx = r * 256 + tid;          // chunk id, 512 per tile
            const int row = idx >> 2;
            const int col = (idx & 3) << 3;
            *(u32x4*)&As[idx * 8] = *(const u32x4*)&A[(size_t)(m0 + row) * DM + kt + col];
            *(u32x4*)&Bs[idx * 8] = *(const u32x4*)&B[(size_t)(n0 + row) * DM + kt + col];
        }
        __syncthreads();
        bf16x8 af[4], bfr[4];
        #pragma unroll
        for (int i = 0; i < 4; i++) af[i]  = *(const bf16x8*)&As[(wr * 64 + i * 16 + lo) * 32 + hi * 8];
        #pragma unroll
        for (int j = 0; j < 4; j++) bfr[j] = *(const bf16x8*)&Bs[(wc * 64 + j * 16 + lo) * 32 + hi * 8];
        #pragma unroll
        for (int i = 0; i < 4; i++)
            #pragma unroll
            for (int j = 0; j < 4; j++)
                acc[i][j] = __builtin_amdgcn_mfma_f32_16x16x32_bf16(af[i], bfr[j], acc[i][j], 0, 0, 0);
        __syncthreads();
    }
}

// ======== QKV projection -> Q/K head-major [b,h,t,d]; V TRANSPOSED [b,g,d,t]
__global__ __launch_bounds__(256) void gemm_qkv(
    const u16* __restrict__ xb, const u16* __restrict__ wt,
    const float* __restrict__ qb, const float* __restrict__ kb,
    const float* __restrict__ vb,
    u16* __restrict__ Q, u16* __restrict__ K, u16* __restrict__ Vt)
{
    __shared__ __align__(16) u16 As[128 * 32];
    __shared__ __align__(16) u16 Bs[128 * 32];
    const int m0 = blockIdx.x * 128;
    const int n0 = blockIdx.y * 128;
    f32x4 acc[4][4];
    gemm128_body(xb, wt, m0, n0, As, Bs, acc);

    const int tid = threadIdx.x;
    const int lane = tid & 63, wid = tid >> 6;
    const int wr = wid >> 1, wc = wid & 1;
    const int lo = lane & 15, hi = lane >> 4;

    #pragma unroll
    for (int j = 0; j < 4; j++) {
        const int n = n0 + wc * 64 + j * 16 + lo;
        u16* outp; int nl, Hcnt, isV = 0; float bias;
        if (n < 768)       { outp = Q;  nl = n;        Hcnt = NHEAD; bias = qb[n];  }
        else if (n < 1024) { outp = K;  nl = n - 768;  Hcnt = KVH;   bias = kb[nl]; }
        else               { outp = Vt; nl = n - 1024; Hcnt = KVH;   bias = vb[nl]; isV = 1; }
        const int head = nl >> 6, d = nl & 63;
        #pragma unroll
        for (int i = 0; i < 4; i++) {
            #pragma unroll
            for (int r = 0; r < 4; r++) {
                const int m = m0 + wr * 64 + i * 16 + hi * 4 + r;
                const int b = m >> 10, t = m & 1023;
                const u16 val = f2bf(acc[i][j][r] + bias);
                if (isV)
                    outp[(((size_t)(b * KVH + head)) * HD + d) * SEQ + t] = val;
                else
                    outp[(((size_t)(b * Hcnt + head)) * SEQ + t) * HD + d] = val;
            }
        }
    }
}

// ======== output projection: attn[8192][768] bf16 @ Wo^T + ob -> fp32 =======
__global__ __launch_bounds__(256) void gemm_oproj(
    const u16* __restrict__ Ab, const u16* __restrict__ wt,
    const float* __restrict__ ob, float* __restrict__ outp)
{
    __shared__ __align__(16) u16 As[128 * 32];
    __shared__ __align__(16) u16 Bs[128 * 32];
    const int m0 = blockIdx.x * 128;
    const int n0 = blockIdx.y * 128;
    f32x4 acc[4][4];
    gemm128_body(Ab, wt, m0, n0, As, Bs, acc);

    const int tid = threadIdx.x;
    const int lane = tid & 63, wid = tid >> 6;
    const int wr = wid >> 1, wc = wid & 1;
    const int lo = lane & 15, hi = lane >> 4;

    #pragma unroll
    for (int j = 0; j < 4; j++) {
        const int n = n0 + wc * 64 + j * 16 + lo;
        const float bias = ob[n];
        #pragma unroll
        for (int i = 0; i < 4; i++) {
            #pragma unroll
            for (int r = 0; r < 4; r++) {
                const int m = m0 + wr * 64 + i * 16 + hi * 4 + r;
                outp[(size_t)m * DM + n] = acc[i][j][r] + bias;
            }
        }
    }
}

// ======== naive RoPE, out-of-place, INTERLEAVED (file-faithful) variant ======
__global__ __launch_bounds__(256) void rope_naive(
    const __hip_bfloat16* __restrict__ in, __hip_bfloat16* __restrict__ outb,
    const int* __restrict__ pos, long long nrows)
{
    const long long gid = (long long)blockIdx.x * 256 + threadIdx.x;
    if (gid >= nrows * 64) return;
    const long long row = gid >> 6;
    const int j = (int)(gid & 63);
    const int t = (int)(row & (SEQ - 1));

    float p;
    if (pos[1] == 1)                              p = (float)pos[t];
    else if (((const float*)pos)[1] == 1.0f)      p = ((const float*)pos)[t];
    else                                          p = (float)pos[2 * t];

    const float inv = exp2f(-(float)(j & 31) * (13.287712379549449f / 32.0f));
    float sv, cv;
    sincosf(p * inv, &sv, &cv);
    const int partner = (j & 1) * 32 + (j >> 1) + ((j < 32) ? 16 : -16);
    const float sign  = (j < 32) ? -1.0f : 1.0f;
    const float val  = __bfloat162float(in[row * HD + j]);
    const float pv   = __bfloat162float(in[row * HD + partner]);
    outb[row * HD + j] = __float2bfloat16(val * cv + sign * pv * sv);
}

// ======== flash-style MFMA attention =========================================
// Grid: b*(NHEAD*16) + h*16 + qt.  4 waves/block, wave owns 16 q-rows.
// No LDS, no barriers: K [b,g,s,d] and Vt [b,g,d,s] read direct (L2-resident).
// Swapped QK^T (A=K,B=Q): lane holds scores for q = qw0+lo at
// s = s0 + sh*16 + hi*4 + r.  These feed PV's A-operand directly under the
// shared k-permutation sigma(hi,e) = 16*(e>>2) + 4*hi + (e&3); Vt fragments
// load with the same sigma (two 8B loads/lane).  Online softmax w/ defer-max.
__global__ __launch_bounds__(256) void attn_mfma(
    const u16* __restrict__ Q, const u16* __restrict__ K,
    const u16* __restrict__ Vt, u16* __restrict__ outp)
{
    const int blk = blockIdx.x;
    const int b   = blk / (NHEAD * 16);
    const int rem = blk % (NHEAD * 16);
    const int h   = rem / 16;
    const int qt  = rem % 16;
    const int g   = h / REP;
    const int wid  = threadIdx.x >> 6;
    const int lane = threadIdx.x & 63;
    const int lo = lane & 15, hi = lane >> 4;

    const int qw0 = qt * 64 + wid * 16;     // first q-row of this wave
    const u16* Qp = Q  + ((size_t)(b * NHEAD + h) * SEQ + qw0) * HD;
    const u16* Kp = K  + (size_t)(b * KVH + g) * SEQ * HD;
    const u16* Vp = Vt + (size_t)(b * KVH + g) * SEQ * HD;   // [d][s]

    // Q fragments (B-operand): row=lo (q), k elems at kk*32 + hi*8
    bf16x8 qf0 = *(const bf16x8*)&Qp[(size_t)lo * HD + hi * 8];
    bf16x8 qf1 = *(const bf16x8*)&Qp[(size_t)lo * HD + 32 + hi * 8];

    f32x4 Oacc[4];
    const f32x4 z = {0.f, 0.f, 0.f, 0.f};
    Oacc[0] = z; Oacc[1] = z; Oacc[2] = z; Oacc[3] = z;
    float m = -3.0e38f, l = 0.f;

    const int nst = (qw0 >> 5) + 1;
    for (int st = 0; st < nst; ++st) {
        const int s0 = st * 32;
        f32x4 accs0 = z, accs1 = z;
        {
            const u16* kr0 = &Kp[(size_t)(s0 + lo) * HD + hi * 8];
            const u16* kr1 = &Kp[(size_t)(s0 + 16 + lo) * HD + hi * 8];
            bf16x8 ka = *(const bf16x8*)&kr0[0];
            bf16x8 kb_ = *(const bf16x8*)&kr0[32];
            bf16x8 kc = *(const bf16x8*)&kr1[0];
            bf16x8 kd = *(const bf16x8*)&kr1[32];
            accs0 = __builtin_amdgcn_mfma_f32_16x16x32_bf16(ka, qf0, accs0, 0, 0, 0);
            accs0 = __builtin_amdgcn_mfma_f32_16x16x32_bf16(kb_, qf1, accs0, 0, 0, 0);
            accs1 = __builtin_amdgcn_mfma_f32_16x16x32_bf16(kc, qf0, accs1, 0, 0, 0);
            accs1 = __builtin_amdgcn_mfma_f32_16x16x32_bf16(kd, qf1, accs1, 0, 0, 0);
        }
        // scale + causal mask (only last tile can touch the diagonal)
        float sc[8];
        float pmax = -3.0e38f;
        const int qrow = qw0 + lo;
        #pragma unroll
        for (int e = 0; e < 8; ++e) {
            float v = ((e < 4) ? accs0[e & 3] : accs1[e & 3]) * 0.125f;
            if (st == nst - 1) {
                const int s = s0 + (e >> 2) * 16 + hi * 4 + (e & 3);
                if (s > qrow) v = -3.0e38f;
            }
            sc[e] = v;
            pmax = fmaxf(pmax, v);
        }
        pmax = fmaxf(pmax, __shfl_xor(pmax, 16));
        pmax = fmaxf(pmax, __shfl_xor(pmax, 32));

        if (!__all(pmax - m <= 8.0f)) {          // defer-max (T13, THR=8)
            const float mn = fmaxf(m, pmax);
            const float f = __expf(m - mn);      // m=-3e38 first time -> f=0
            l *= f;
            #pragma unroll
            for (int r = 0; r < 4; ++r) {
                const float fr = __shfl(f, hi * 4 + r);
                Oacc[0][r] *= fr; Oacc[1][r] *= fr;
                Oacc[2][r] *= fr; Oacc[3][r] *= fr;
            }
            m = mn;
        }

        float psum = 0.f;
        union { u16 u[8]; bf16x8 v; } pu;
        #pragma unroll
        for (int e = 0; e < 8; ++e) {
            const float p = __expf(sc[e] - m);   // bounded by e^8
            psum += p;
            pu.u[e] = f2bf(p);
        }
        psum += __shfl_xor(psum, 16);
        psum += __shfl_xor(psum, 32);
        l += psum;

        // PV: A=P (rows=q by lo), B=Vt fragments with matching sigma
        #pragma unroll
        for (int dj = 0; dj < 4; ++dj) {
            const u16* vr = &Vp[(size_t)(dj * 16 + lo) * SEQ + s0 + hi * 4];
            union { unsigned long long q[2]; bf16x8 v; } vu;
            vu.q[0] = *(const unsigned long long*)&vr[0];   // e0..3: s0+4hi+0..3
            vu.q[1] = *(const unsigned long long*)&vr[16];  // e4..7: +16
            Oacc[dj] = __builtin_amdgcn_mfma_f32_16x16x32_bf16(pu.v, vu.v, Oacc[dj], 0, 0, 0);
        }
    }

    // epilogue: O[q = qw0 + hi*4 + r][d = dj*16 + lo] / l
    #pragma unroll
    for (int r = 0; r < 4; ++r) {
        const float lr = __shfl(l, hi * 4 + r);
        const float linv = 1.0f / fmaxf(lr, 1e-37f);
        const int t = qw0 + hi * 4 + r;
        #pragma unroll
        for (int dj = 0; dj < 4; ++dj)
            outp[((size_t)(b * SEQ + t)) * DM + h * HD + dj * 16 + lo] =
                f2bf(Oacc[dj][r] * linv);
    }
}

extern "C" void kernel_launch(void* const* d_in, const int* in_sizes, int n_in,
                              void* d_out, int out_size, void* d_ws, size_t ws_size,
                              hipStream_t stream) {
    const float* x   = (const float*)d_in[0];
    const int*   pos = (const int*)d_in[1];
    const float* qw  = (const float*)d_in[2];
    const float* qb  = (const float*)d_in[3];
    const float* kw  = (const float*)d_in[4];
    const float* kb  = (const float*)d_in[5];
    const float* vw  = (const float*)d_in[6];
    const float* vb  = (const float*)d_in[7];
    const float* ow  = (const float*)d_in[8];
    const float* ob  = (const float*)d_in[9];
    float* out = (float*)d_out;                 // OUTPUT IS FP32

    u16* xb    = (u16*)d_ws;                                    // 6291456
    u16* Wqkvt = xb    + (size_t)8192 * DM;                     //  983040
    u16* Wot   = Wqkvt + (size_t)1280 * DM;                     //  589824
    u16* Qbuf  = Wot   + (size_t)DM * DM;                       // 6291456
    u16* Kbuf  = Qbuf  + (size_t)BATCH * NHEAD * SEQ * HD;      // 2097152
    u16* Krot  = Kbuf  + (size_t)BATCH * KVH * SEQ * HD;        // 2097152
    u16* Vtb   = Krot  + (size_t)BATCH * KVH * SEQ * HD;        // 2097152 [b,g,d,s]
    u16* Qrot  = xb;     // alias: xb dead after gemm_qkv
    u16* attn  = Qbuf;   // alias: Qbuf dead after rope_q

    cvt_x_k<<<(8192 * DM / 4 + 255) / 256, 256, 0, stream>>>(x, xb, 8192 * DM / 4);
    cvt_wqkv_k<<<(1280 * DM + 255) / 256, 256, 0, stream>>>(qw, kw, vw, Wqkvt);
    cvt_wo_k<<<(DM * DM + 255) / 256, 256, 0, stream>>>(ow, Wot);

    dim3 gq(64, 10);   // M/128=64, N/128=10 (N=1280)
    gemm_qkv<<<gq, 256, 0, stream>>>(xb, Wqkvt, qb, kb, vb, Qbuf, Kbuf, Vtb);

    const long long qrows = (long long)BATCH * NHEAD * SEQ;   // 98304
    const long long krows = (long long)BATCH * KVH * SEQ;     // 32768
    rope_naive<<<(int)((qrows * 64 + 255) / 256), 256, 0, stream>>>(
        (const __hip_bfloat16*)Qbuf, (__hip_bfloat16*)Qrot, pos, qrows);
    rope_naive<<<(int)((krows * 64 + 255) / 256), 256, 0, stream>>>(
        (const __hip_bfloat16*)Kbuf, (__hip_bfloat16*)Krot, pos, krows);

    attn_mfma<<<BATCH * NHEAD * 16, 256, 0, stream>>>(Qrot, Krot, Vtb, attn);

    dim3 go(64, 6);    // N=768
    gemm_oproj<<<go, 256, 0, stream>>>(attn, Wot, ob, out);
}

// Round 3
// 276.357 us; speedup vs baseline: 16.0708x; 1.6627x over previous
//
#include <hip/hip_runtime.h>
#include <hip/hip_bf16.h>
#include <math.h>

#define BATCH 8
#define SEQ   1024
#define DM    768
#define NHEAD 12
#define KVH   4
#define HD    64
#define REP   3

typedef unsigned short u16;
typedef __attribute__((ext_vector_type(8))) __bf16 bf16x8;
typedef __attribute__((ext_vector_type(4))) float f32x4;
typedef __attribute__((ext_vector_type(4))) unsigned int u32x4;

// RTNE fp32 -> bf16 (finite values)
__device__ __forceinline__ u16 f2bf(float f) {
    unsigned int u = __float_as_uint(f);
    u += 0x7fffu + ((u >> 16) & 1u);
    return (u16)(u >> 16);
}

// ======== convert x -> bf16, vectorized (float4 in, ushort4 out) ============
__global__ __launch_bounds__(256) void cvt_x_k(
    const float* __restrict__ in, u16* __restrict__ o, int n4)
{
    const int i = blockIdx.x * 256 + threadIdx.x;
    if (i >= n4) return;
    const float4 v = ((const float4*)in)[i];
    ushort4 r;
    r.x = f2bf(v.x); r.y = f2bf(v.y); r.z = f2bf(v.z); r.w = f2bf(v.w);
    ((ushort4*)o)[i] = r;
}

// ==== build Wt[n][k] bf16 = concat(qw|kw|vw)[k][n] transposed+converted =====
__global__ __launch_bounds__(256) void cvt_wqkv_k(
    const float* __restrict__ qw, const float* __restrict__ kw,
    const float* __restrict__ vw, u16* __restrict__ wt)
{
    const int idx = blockIdx.x * 256 + threadIdx.x;   // idx = n*768 + k
    if (idx >= 1280 * DM) return;
    const int k = idx % DM;
    const int n = idx / DM;
    float v;
    if (n < 768)       v = qw[(size_t)k * 768 + n];
    else if (n < 1024) v = kw[(size_t)k * 256 + (n - 768)];
    else               v = vw[(size_t)k * 256 + (n - 1024)];
    wt[idx] = f2bf(v);
}

__global__ __launch_bounds__(256) void cvt_wo_k(
    const float* __restrict__ ow, u16* __restrict__ wt)
{
    const int idx = blockIdx.x * 256 + threadIdx.x;   // idx = n*768 + k
    if (idx >= DM * DM) return;
    const int k = idx % DM;
    const int n = idx / DM;
    wt[idx] = f2bf(ow[(size_t)k * DM + n]);
}

// ======== 128x128-tile bf16 MFMA GEMM body (single-buffer, BK=32) ===========
__device__ __forceinline__ void gemm128_body(
    const u16* __restrict__ A, const u16* __restrict__ B,
    int m0, int n0, u16* As, u16* Bs, f32x4 acc[4][4])
{
    const int tid  = threadIdx.x;
    const int lane = tid & 63;
    const int wid  = tid >> 6;
    const int wr = wid >> 1, wc = wid & 1;
    const int lo = lane & 15, hi = lane >> 4;

    const f32x4 z = {0.f, 0.f, 0.f, 0.f};
    #pragma unroll
    for (int i = 0; i < 4; i++)
        #pragma unroll
        for (int j = 0; j < 4; j++)
            acc[i][j] = z;

    for (int kt = 0; kt < DM; kt += 32) {
        #pragma unroll
        for (int r = 0; r < 2; ++r) {
            const int idx = r * 256 + tid;          // chunk id, 512 per tile
            const int row = idx >> 2;
            const int col = (idx & 3) << 3;
            *(u32x4*)&As[idx * 8] = *(const u32x4*)&A[(size_t)(m0 + row) * DM + kt + col];
            *(u32x4*)&Bs[idx * 8] = *(const u32x4*)&B[(size_t)(n0 + row) * DM + kt + col];
        }
        __syncthreads();
        bf16x8 af[4], bfr[4];
        #pragma unroll
        for (int i = 0; i < 4; i++) af[i]  = *(const bf16x8*)&As[(wr * 64 + i * 16 + lo) * 32 + hi * 8];
        #pragma unroll
        for (int j = 0; j < 4; j++) bfr[j] = *(const bf16x8*)&Bs[(wc * 64 + j * 16 + lo) * 32 + hi * 8];
        #pragma unroll
        for (int i = 0; i < 4; i++)
            #pragma unroll
            for (int j = 0; j < 4; j++)
                acc[i][j] = __builtin_amdgcn_mfma_f32_16x16x32_bf16(af[i], bfr[j], acc[i][j], 0, 0, 0);
        __syncthreads();
    }
}

// ======== QKV projection -> Q/K head-major [b,h,t,d]; V TRANSPOSED [b,g,d,t]
__global__ __launch_bounds__(256) void gemm_qkv(
    const u16* __restrict__ xb, const u16* __restrict__ wt,
    const float* __restrict__ qb, const float* __restrict__ kb,
    const float* __restrict__ vb,
    u16* __restrict__ Q, u16* __restrict__ K, u16* __restrict__ Vt)
{
    __shared__ __align__(16) u16 As[128 * 32];
    __shared__ __align__(16) u16 Bs[128 * 32];
    const int m0 = blockIdx.x * 128;
    const int n0 = blockIdx.y * 128;
    f32x4 acc[4][4];
    gemm128_body(xb, wt, m0, n0, As, Bs, acc);

    const int tid = threadIdx.x;
    const int lane = tid & 63, wid = tid >> 6;
    const int wr = wid >> 1, wc = wid & 1;
    const int lo = lane & 15, hi = lane >> 4;

    #pragma unroll
    for (int j = 0; j < 4; j++) {
        const int n = n0 + wc * 64 + j * 16 + lo;
        if (n < 1024) {       // Q or K: [b,h,t,d] layout, scalar stores
            u16* outp; int nl, Hcnt; float bias;
            if (n < 768) { outp = Q; nl = n;       Hcnt = NHEAD; bias = qb[n];  }
            else         { outp = K; nl = n - 768; Hcnt = KVH;   bias = kb[nl]; }
            const int head = nl >> 6, d = nl & 63;
            #pragma unroll
            for (int i = 0; i < 4; i++) {
                #pragma unroll
                for (int r = 0; r < 4; r++) {
                    const int m = m0 + wr * 64 + i * 16 + hi * 4 + r;
                    const int b = m >> 10, t = m & 1023;
                    outp[(((size_t)(b * Hcnt + head)) * SEQ + t) * HD + d] =
                        f2bf(acc[i][j][r] + bias);
                }
            }
        } else {              // V: [b,g,d,t] layout, ushort4 stores (4 consecutive t)
            const int nl = n - 1024;
            const float bias = vb[nl];
            const int head = nl >> 6, d = nl & 63;
            #pragma unroll
            for (int i = 0; i < 4; i++) {
                ushort4 vs;
                vs.x = f2bf(acc[i][j][0] + bias);
                vs.y = f2bf(acc[i][j][1] + bias);
                vs.z = f2bf(acc[i][j][2] + bias);
                vs.w = f2bf(acc[i][j][3] + bias);
                const int m = m0 + wr * 64 + i * 16 + hi * 4;
                const int b = m >> 10, t = m & 1023;
                *(ushort4*)&Vt[(((size_t)(b * KVH + head)) * HD + d) * SEQ + t] = vs;
            }
        }
    }
}

// ======== output projection: attn[8192][768] bf16 @ Wo^T + ob -> fp32 =======
__global__ __launch_bounds__(256) void gemm_oproj(
    const u16* __restrict__ Ab, const u16* __restrict__ wt,
    const float* __restrict__ ob, float* __restrict__ outp)
{
    __shared__ __align__(16) u16 As[128 * 32];
    __shared__ __align__(16) u16 Bs[128 * 32];
    const int m0 = blockIdx.x * 128;
    const int n0 = blockIdx.y * 128;
    f32x4 acc[4][4];
    gemm128_body(Ab, wt, m0, n0, As, Bs, acc);

    const int tid = threadIdx.x;
    const int lane = tid & 63, wid = tid >> 6;
    const int wr = wid >> 1, wc = wid & 1;
    const int lo = lane & 15, hi = lane >> 4;

    #pragma unroll
    for (int j = 0; j < 4; j++) {
        const int n = n0 + wc * 64 + j * 16 + lo;
        const float bias = ob[n];
        #pragma unroll
        for (int i = 0; i < 4; i++) {
            #pragma unroll
            for (int r = 0; r < 4; r++) {
                const int m = m0 + wr * 64 + i * 16 + hi * 4 + r;
                outp[(size_t)m * DM + n] = acc[i][j][r] + bias;
            }
        }
    }
}

// ======== naive RoPE, out-of-place, INTERLEAVED (file-faithful) variant ======
__global__ __launch_bounds__(256) void rope_naive(
    const __hip_bfloat16* __restrict__ in, __hip_bfloat16* __restrict__ outb,
    const int* __restrict__ pos, long long nrows)
{
    const long long gid = (long long)blockIdx.x * 256 + threadIdx.x;
    if (gid >= nrows * 64) return;
    const long long row = gid >> 6;
    const int j = (int)(gid & 63);
    const int t = (int)(row & (SEQ - 1));

    float p;
    if (pos[1] == 1)                              p = (float)pos[t];
    else if (((const float*)pos)[1] == 1.0f)      p = ((const float*)pos)[t];
    else                                          p = (float)pos[2 * t];

    const float inv = exp2f(-(float)(j & 31) * (13.287712379549449f / 32.0f));
    float sv, cv;
    sincosf(p * inv, &sv, &cv);
    const int partner = (j & 1) * 32 + (j >> 1) + ((j < 32) ? 16 : -16);
    const float sign  = (j < 32) ? -1.0f : 1.0f;
    const float val  = __bfloat162float(in[row * HD + j]);
    const float pv   = __bfloat162float(in[row * HD + partner]);
    outb[row * HD + j] = __float2bfloat16(val * cv + sign * pv * sv);
}

// ======== flash-style MFMA attention, v3 ====================================
// Grid 768 = 96 (b,h) x 8.  4 waves/block; wave wid of block c owns q-block
// a = c + 8*wid (32 q-rows [32a, 32a+32), two 16-row strips A/B sharing all
// K/V loads).  Balanced: per-block max nst spread is 25..32.  No LDS/barriers.
// Fragment math identical to verified round-2 kernel (swapped QK^T, shared
// sigma(hi,e)=16(e>>2)+4hi+(e&3) for P and Vt).  V issued before QK, next K
// prefetched before softmax; setprio around MFMA clusters (T5).
__global__ __launch_bounds__(256, 2) void attn_mfma(
    const u16* __restrict__ Q, const u16* __restrict__ K,
    const u16* __restrict__ Vt, u16* __restrict__ outp)
{
    // bijective XCD swizzle (768 % 8 == 0): XCD x gets 12 contiguous (b,h)
    const int wg = (blockIdx.x & 7) * 96 + (blockIdx.x >> 3);
    const int bh = wg >> 3;
    const int c  = wg & 7;
    const int b  = bh / NHEAD, h = bh % NHEAD;
    const int g  = h / REP;
    const int wid  = threadIdx.x >> 6;
    const int lane = threadIdx.x & 63;
    const int lo = lane & 15, hi = lane >> 4;

    const int a   = c + (wid << 3);          // 0..31
    const int q0  = a << 5;                  // 32 q-rows
    const int nst = a + 1;

    const u16* Qp = Q  + ((size_t)(b * NHEAD + h) * SEQ + q0) * HD;
    const u16* Kp = K  + (size_t)(b * KVH + g) * SEQ * HD;
    const u16* Vp = Vt + (size_t)(b * KVH + g) * SEQ * HD;   // [d][s]

    // Q fragments (B-operand): strips A (q0+lo) and B (q0+16+lo)
    const bf16x8 qA0 = *(const bf16x8*)&Qp[(size_t)lo * HD + hi * 8];
    const bf16x8 qA1 = *(const bf16x8*)&Qp[(size_t)lo * HD + 32 + hi * 8];
    const bf16x8 qB0 = *(const bf16x8*)&Qp[(size_t)(16 + lo) * HD + hi * 8];
    const bf16x8 qB1 = *(const bf16x8*)&Qp[(size_t)(16 + lo) * HD + 32 + hi * 8];

    const f32x4 z = {0.f, 0.f, 0.f, 0.f};
    f32x4 OA[4], OB[4];
    #pragma unroll
    for (int dj = 0; dj < 4; ++dj) { OA[dj] = z; OB[dj] = z; }
    float mA = -3.0e38f, lA = 0.f, mB = -3.0e38f, lB = 0.f;

    // K prefetch for st = 0
    bf16x8 k0, k1, k2, k3;
    {
        const u16* kr0 = &Kp[(size_t)lo * HD + hi * 8];
        const u16* kr1 = &Kp[(size_t)(16 + lo) * HD + hi * 8];
        k0 = *(const bf16x8*)&kr0[0];  k1 = *(const bf16x8*)&kr0[32];
        k2 = *(const bf16x8*)&kr1[0];  k3 = *(const bf16x8*)&kr1[32];
    }

    for (int st = 0; st < nst; ++st) {
        const int s0 = st << 5;

        // V loads for this tile (issued early, consumed after softmax)
        union { unsigned long long q[2]; bf16x8 v; } vu[4];
        #pragma unroll
        for (int dj = 0; dj < 4; ++dj) {
            const u16* vr = &Vp[(size_t)(dj * 16 + lo) * SEQ + s0 + hi * 4];
            vu[dj].q[0] = *(const unsigned long long*)&vr[0];
            vu[dj].q[1] = *(const unsigned long long*)&vr[16];
        }

        // QK^T for both strips (A = K rows, B = Q)
        f32x4 sA0 = z, sA1 = z, sB0 = z, sB1 = z;
        __builtin_amdgcn_s_setprio(1);
        sA0 = __builtin_amdgcn_mfma_f32_16x16x32_bf16(k0, qA0, sA0, 0, 0, 0);
        sA0 = __builtin_amdgcn_mfma_f32_16x16x32_bf16(k1, qA1, sA0, 0, 0, 0);
        sA1 = __builtin_amdgcn_mfma_f32_16x16x32_bf16(k2, qA0, sA1, 0, 0, 0);
        sA1 = __builtin_amdgcn_mfma_f32_16x16x32_bf16(k3, qA1, sA1, 0, 0, 0);
        sB0 = __builtin_amdgcn_mfma_f32_16x16x32_bf16(k0, qB0, sB0, 0, 0, 0);
        sB0 = __builtin_amdgcn_mfma_f32_16x16x32_bf16(k1, qB1, sB0, 0, 0, 0);
        sB1 = __builtin_amdgcn_mfma_f32_16x16x32_bf16(k2, qB0, sB1, 0, 0, 0);
        sB1 = __builtin_amdgcn_mfma_f32_16x16x32_bf16(k3, qB1, sB1, 0, 0, 0);
        __builtin_amdgcn_s_setprio(0);

        // prefetch K for st+1 (overlaps softmax)
        if (st + 1 < nst) {
            const u16* kr0 = &Kp[(size_t)(s0 + 32 + lo) * HD + hi * 8];
            const u16* kr1 = &Kp[(size_t)(s0 + 48 + lo) * HD + hi * 8];
            k0 = *(const bf16x8*)&kr0[0];  k1 = *(const bf16x8*)&kr0[32];
            k2 = *(const bf16x8*)&kr1[0];  k3 = *(const bf16x8*)&kr1[32];
        }

        // scale + causal mask (only the diagonal tile st == a)
        float scA[8], scB[8];
        #pragma unroll
        for (int e = 0; e < 8; ++e) {
            scA[e] = ((e < 4) ? sA0[e & 3] : sA1[e & 3]) * 0.125f;
            scB[e] = ((e < 4) ? sB0[e & 3] : sB1[e & 3]) * 0.125f;
        }
        if (st == a) {
            #pragma unroll
            for (int e = 0; e < 8; ++e) {
                const int srel = ((e >> 2) << 4) + (hi << 2) + (e & 3);
                if (srel > lo)      scA[e] = -3.0e38f;
                if (srel > 16 + lo) scB[e] = -3.0e38f;
            }
        }

        float pmA = scA[0], pmB = scB[0];
        #pragma unroll
        for (int e = 1; e < 8; ++e) { pmA = fmaxf(pmA, scA[e]); pmB = fmaxf(pmB, scB[e]); }
        pmA = fmaxf(pmA, __shfl_xor(pmA, 16)); pmA = fmaxf(pmA, __shfl_xor(pmA, 32));
        pmB = fmaxf(pmB, __shfl_xor(pmB, 16)); pmB = fmaxf(pmB, __shfl_xor(pmB, 32));

        if (!__all(pmA - mA <= 8.0f && pmB - mB <= 8.0f)) {   // defer-max (T13)
            const float mnA = fmaxf(mA, pmA), mnB = fmaxf(mB, pmB);
            const float fA = __expf(mA - mnA), fB = __expf(mB - mnB);
            lA *= fA; lB *= fB;
            #pragma unroll
            for (int r = 0; r < 4; ++r) {
                const float frA = __shfl(fA, hi * 4 + r);
                const float frB = __shfl(fB, hi * 4 + r);
                #pragma unroll
                for (int dj = 0; dj < 4; ++dj) { OA[dj][r] *= frA; OB[dj][r] *= frB; }
            }
            mA = mnA; mB = mnB;
        }

        union { u16 u[8]; bf16x8 v; } puA, puB;
        float psA = 0.f, psB = 0.f;
        #pragma unroll
        for (int e = 0; e < 8; ++e) {
            const float pA = __expf(scA[e] - mA);
            const float pB = __expf(scB[e] - mB);
            psA += pA; psB += pB;
            puA.u[e] = f2bf(pA); puB.u[e] = f2bf(pB);
        }
        psA += __shfl_xor(psA, 16); psA += __shfl_xor(psA, 32);
        psB += __shfl_xor(psB, 16); psB += __shfl_xor(psB, 32);
        lA += psA; lB += psB;

        // PV: A = P, B = Vt fragments (shared across strips)
        __builtin_amdgcn_s_setprio(1);
        #pragma unroll
        for (int dj = 0; dj < 4; ++dj) {
            OA[dj] = __builtin_amdgcn_mfma_f32_16x16x32_bf16(puA.v, vu[dj].v, OA[dj], 0, 0, 0);
            OB[dj] = __builtin_amdgcn_mfma_f32_16x16x32_bf16(puB.v, vu[dj].v, OB[dj], 0, 0, 0);
        }
        __builtin_amdgcn_s_setprio(0);
    }

    // epilogue: strip S row q = q0 + 16S + hi*4 + r, col d = dj*16 + lo
    #pragma unroll
    for (int r = 0; r < 4; ++r) {
        const float lrA = __shfl(lA, hi * 4 + r);
        const float lrB = __shfl(lB, hi * 4 + r);
        const float liA = 1.0f / fmaxf(lrA, 1e-37f);
        const float liB = 1.0f / fmaxf(lrB, 1e-37f);
        const int tA = q0 + hi * 4 + r;
        const int tB = tA + 16;
        #pragma unroll
        for (int dj = 0; dj < 4; ++dj) {
            outp[((size_t)(b * SEQ + tA)) * DM + h * HD + dj * 16 + lo] = f2bf(OA[dj][r] * liA);
            outp[((size_t)(b * SEQ + tB)) * DM + h * HD + dj * 16 + lo] = f2bf(OB[dj][r] * liB);
        }
    }
}

extern "C" void kernel_launch(void* const* d_in, const int* in_sizes, int n_in,
                              void* d_out, int out_size, void* d_ws, size_t ws_size,
                              hipStream_t stream) {
    const float* x   = (const float*)d_in[0];
    const int*   pos = (const int*)d_in[1];
    const float* qw  = (const float*)d_in[2];
    const float* qb  = (const float*)d_in[3];
    const float* kw  = (const float*)d_in[4];
    const float* kb  = (const float*)d_in[5];
    const float* vw  = (const float*)d_in[6];
    const float* vb  = (const float*)d_in[7];
    const float* ow  = (const float*)d_in[8];
    const float* ob  = (const float*)d_in[9];
    float* out = (float*)d_out;                 // OUTPUT IS FP32

    u16* xb    = (u16*)d_ws;                                    // 6291456
    u16* Wqkvt = xb    + (size_t)8192 * DM;                     //  983040
    u16* Wot   = Wqkvt + (size_t)1280 * DM;                     //  589824
    u16* Qbuf  = Wot   + (size_t)DM * DM;                       // 6291456
    u16* Kbuf  = Qbuf  + (size_t)BATCH * NHEAD * SEQ * HD;      // 2097152
    u16* Krot  = Kbuf  + (size_t)BATCH * KVH * SEQ * HD;        // 2097152
    u16* Vtb   = Krot  + (size_t)BATCH * KVH * SEQ * HD;        // 2097152 [b,g,d,s]
    u16* Qrot  = xb;     // alias: xb dead after gemm_qkv
    u16* attn  = Qbuf;   // alias: Qbuf dead after rope_q

    cvt_x_k<<<(8192 * DM / 4 + 255) / 256, 256, 0, stream>>>(x, xb, 8192 * DM / 4);
    cvt_wqkv_k<<<(1280 * DM + 255) / 256, 256, 0, stream>>>(qw, kw, vw, Wqkvt);
    cvt_wo_k<<<(DM * DM + 255) / 256, 256, 0, stream>>>(ow, Wot);

    dim3 gq(64, 10);   // M/128=64, N/128=10 (N=1280)
    gemm_qkv<<<gq, 256, 0, stream>>>(xb, Wqkvt, qb, kb, vb, Qbuf, Kbuf, Vtb);

    const long long qrows = (long long)BATCH * NHEAD * SEQ;   // 98304
    const long long krows = (long long)BATCH * KVH * SEQ;     // 32768
    rope_naive<<<(int)((qrows * 64 + 255) / 256), 256, 0, stream>>>(
        (const __hip_bfloat16*)Qbuf, (__hip_bfloat16*)Qrot, pos, qrows);
    rope_naive<<<(int)((krows * 64 + 255) / 256), 256, 0, stream>>>(
        (const __hip_bfloat16*)Kbuf, (__hip_bfloat16*)Krot, pos, krows);

    attn_mfma<<<96 * 8, 256, 0, stream>>>(Qrot, Krot, Vtb, attn);

    dim3 go(64, 6);    // N=768
    gemm_oproj<<<go, 256, 0, stream>>>(attn, Wot, ob, out);
}